// Round 8
// baseline (353.395 us; speedup 1.0000x reference)
//
#include <hip/hip_runtime.h>
#include <math.h>

#define B_ 16
#define S_ 512
#define D_ 768
#define H_ 12
#define DH_ 64
#define BH_ (B_*H_)     // 192
#define MTOT (B_*S_)    // 8192
#define NTOT (3*D_)     // 2304

typedef unsigned short ushort_t;
typedef __attribute__((ext_vector_type(8))) short bf16x8;
typedef __attribute__((ext_vector_type(4))) float f32x4;

__device__ __forceinline__ unsigned short f2bf(float x){
    unsigned u = __float_as_uint(x);
    unsigned r = (u + 0x7FFFu + ((u >> 16) & 1u)) >> 16;
    return (unsigned short)r;
}
__device__ __forceinline__ float bf2f(unsigned short b){
    return __uint_as_float(((unsigned)b) << 16);
}

__device__ __forceinline__ void cp16(const void* g, void* l){
    __builtin_amdgcn_global_load_lds(
        (const __attribute__((address_space(1))) unsigned int*)g,
        (__attribute__((address_space(3))) unsigned int*)l, 16, 0, 0);
}

// ---------------------------------------------------------------------------
// f32 -> single bf16 (round-to-nearest), 4 elems/thread
// ---------------------------------------------------------------------------
__global__ __launch_bounds__(256)
void convert_x(const float* __restrict__ src, ushort_t* __restrict__ dst, int n4)
{
    int i = blockIdx.x * 256 + threadIdx.x;
    if (i >= n4) return;
    float4 x = ((const float4*)src)[i];
    union { ushort_t u[4]; uint2 v; } p;
    p.u[0] = f2bf(x.x); p.u[1] = f2bf(x.y);
    p.u[2] = f2bf(x.z); p.u[3] = f2bf(x.w);
    ((uint2*)dst)[i] = p.v;
}

// weights: split hi/lo, all three matrices in one launch
__global__ __launch_bounds__(256)
void convert_w(const float* __restrict__ Wq, const float* __restrict__ Wk,
               const float* __restrict__ Wv, ushort_t* __restrict__ hi,
               ushort_t* __restrict__ lo)
{
    const float* src = (blockIdx.z==0) ? Wq : (blockIdx.z==1) ? Wk : Wv;
    const int n4 = D_*D_/4;
    int i = blockIdx.x * 256 + threadIdx.x;
    if (i >= n4) return;
    size_t off4 = (size_t)blockIdx.z * n4;
    float4 x = ((const float4*)src)[i];
    union { ushort_t u[4]; uint2 v; } ph, pl;
    float xs[4] = {x.x, x.y, x.z, x.w};
    #pragma unroll
    for (int c = 0; c < 4; c++){
        unsigned short h = f2bf(xs[c]);
        ph.u[c] = h;
        pl.u[c] = f2bf(xs[c] - bf2f(h));
    }
    ((uint2*)hi)[off4 + i] = ph.v;
    ((uint2*)lo)[off4 + i] = pl.v;
}

// ---------------------------------------------------------------------------
// MFMA GEMM: C[m,n] = sum_k Xbf[m,k] * W[n,k] + bias; X single bf16, W hi/lo
// (2 MFMAs per tile-pair). mat 0 -> Q hi/lo, 1 -> K hi/lo, 2 -> V f32.
// ---------------------------------------------------------------------------
#define BM 128
#define BN 128
#define BK 32

__global__ __launch_bounds__(256)
void gemm_split(const ushort_t* __restrict__ A,
                const ushort_t* __restrict__ Bhi, const ushort_t* __restrict__ Blo,
                const float* __restrict__ bq, const float* __restrict__ bk,
                const float* __restrict__ bv,
                ushort_t* __restrict__ qhi, ushort_t* __restrict__ qlo,
                ushort_t* __restrict__ khi, ushort_t* __restrict__ klo,
                float* __restrict__ outv)
{
    __shared__ ushort_t Ah[BM*BK], Bh[BN*BK], Bl[BN*BK];  // 24 KB

    const int tid  = threadIdx.x;
    const int lane = tid & 63, wave = tid >> 6;
    const int m0 = blockIdx.y * BM, n0 = blockIdx.x * BN;
    const int wm = (wave >> 1) * 64, wn = (wave & 1) * 64;

    f32x4 acc[4][4];
    #pragma unroll
    for (int i=0;i<4;i++)
        #pragma unroll
        for (int j=0;j<4;j++) acc[i][j] = (f32x4){0.f,0.f,0.f,0.f};

    const int r0 = tid >> 2, c0 = (tid & 3) * 8;
    const size_t ga0 = (size_t)(m0 + r0)      * D_ + c0;
    const size_t ga1 = (size_t)(m0 + 64 + r0) * D_ + c0;
    const size_t gb0 = (size_t)(n0 + r0)      * D_ + c0;
    const size_t gb1 = (size_t)(n0 + 64 + r0) * D_ + c0;
    const int l0 = wave * 512;
    const int l1 = 2048 + wave * 512;

    const int fr = lane & 15, kc = (lane >> 4) * 8;

    for (int k0 = 0; k0 < D_; k0 += BK) {
        cp16(A   + ga0 + k0, Ah + l0);
        cp16(A   + ga1 + k0, Ah + l1);
        cp16(Bhi + gb0 + k0, Bh + l0);
        cp16(Bhi + gb1 + k0, Bh + l1);
        cp16(Blo + gb0 + k0, Bl + l0);
        cp16(Blo + gb1 + k0, Bl + l1);
        __syncthreads();

        bf16x8 fa[4], fbh[4], fbl[4];
        #pragma unroll
        for (int i = 0; i < 4; i++){
            fa[i]  = *(const bf16x8*)&Ah[(wm + i*16 + fr)*BK + kc];
            fbh[i] = *(const bf16x8*)&Bh[(wn + i*16 + fr)*BK + kc];
            fbl[i] = *(const bf16x8*)&Bl[(wn + i*16 + fr)*BK + kc];
        }
        #pragma unroll
        for (int i = 0; i < 4; i++)
            #pragma unroll
            for (int j = 0; j < 4; j++){
                acc[i][j] = __builtin_amdgcn_mfma_f32_16x16x32_bf16(fa[i], fbh[j], acc[i][j], 0,0,0);
                acc[i][j] = __builtin_amdgcn_mfma_f32_16x16x32_bf16(fa[i], fbl[j], acc[i][j], 0,0,0);
            }
        __syncthreads();
    }

    const int mat = n0 / D_;   // block-uniform
    const float* bias = (mat==0) ? bq : (mat==1) ? bk : bv;
    const int col = lane & 15, rbase = (lane >> 4) * 4;
    #pragma unroll
    for (int j = 0; j < 4; j++){
        int nn = n0 + wn + j*16 + col - mat*D_;
        int h = nn >> 6, d = nn & 63;
        float bsv = bias[nn];
        #pragma unroll
        for (int i = 0; i < 4; i++){
            #pragma unroll
            for (int r = 0; r < 4; r++){
                int m = m0 + wm + i*16 + rbase + r;
                int bb = m >> 9, s = m & 511;
                size_t idx = (((size_t)bb*H_ + h)*S_ + s)*DH_ + d;
                float val = acc[i][j][r] + bsv;
                if (mat == 2) outv[idx] = val;
                else {
                    ushort_t hv = f2bf(val);
                    ushort_t lv = f2bf(val - bf2f(hv));
                    if (mat == 0){ qhi[idx] = hv; qlo[idx] = lv; }
                    else         { khi[idx] = hv; klo[idx] = lv; }
                }
            }
        }
    }
}

// ---------------------------------------------------------------------------
// MFMA sparsemax attention (R5 dispatch order; compacted-support PV).
// Phase 1: wave w computes scores for 16 rows x keys [128w,128w+128) -> LDS.
// Phase 2: wave w owns rows 4w..4w+3 (full 512 keys): Michelot tau (wave-
//   local), then compacts support (p>0) into per-row LDS lists (key index
//   packed in low 9 mantissa bits of p), and runs a counted PV loop with 4
//   independent row-chains -> pipelined V loads. Direct store.
// ---------------------------------------------------------------------------
#define SCPAD 524   // float stride; spreads banks across rows

__global__ __launch_bounds__(256)
void attn_mfma(const ushort_t* __restrict__ Qhi, const ushort_t* __restrict__ Qlo,
               const ushort_t* __restrict__ Khi, const ushort_t* __restrict__ Klo,
               const float* __restrict__ V, const float* __restrict__ mask,
               float* __restrict__ out)
{
    __shared__ float sc[16*SCPAD];   // 33.5 KB scores [row][key]

    const int lane = threadIdx.x & 63;
    const int wave = threadIdx.x >> 6;
    const int fr = lane & 15, quad = lane >> 4;
    const int bh = blockIdx.x >> 5;            // R5 order: same-head adjacent
    const int q0 = (blockIdx.x & 31) * 16;
    const int b = bh / H_, h = bh % H_;
    const size_t hb = (size_t)bh * S_ * DH_;
    const int kw0 = wave * 128;                // phase-1 key range

    // Q A-fragments: row = fr (q0+fr), k = quad*8 + [0..8)
    bf16x8 qh[2], ql[2];
    {
        const ushort_t* qp  = Qhi + hb + (size_t)(q0 + fr)*DH_ + quad*8;
        const ushort_t* qp2 = Qlo + hb + (size_t)(q0 + fr)*DH_ + quad*8;
        qh[0] = *(const bf16x8*)qp;   qh[1] = *(const bf16x8*)(qp + 32);
        ql[0] = *(const bf16x8*)qp2;  ql[1] = *(const bf16x8*)(qp2 + 32);
    }

    f32x4 acc[8];
    #pragma unroll
    for (int j=0;j<8;j++) acc[j] = (f32x4){0.f,0.f,0.f,0.f};

    #pragma unroll
    for (int j=0;j<8;j++){
        const ushort_t* kp  = Khi + hb + (size_t)(kw0 + j*16 + fr)*DH_ + quad*8;
        const ushort_t* kp2 = Klo + hb + (size_t)(kw0 + j*16 + fr)*DH_ + quad*8;
        bf16x8 kh0 = *(const bf16x8*)kp;
        bf16x8 kh1 = *(const bf16x8*)(kp + 32);
        bf16x8 kl0 = *(const bf16x8*)kp2;
        bf16x8 kl1 = *(const bf16x8*)(kp2 + 32);
        acc[j] = __builtin_amdgcn_mfma_f32_16x16x32_bf16(qh[0], kh0, acc[j], 0,0,0);
        acc[j] = __builtin_amdgcn_mfma_f32_16x16x32_bf16(qh[1], kh1, acc[j], 0,0,0);
        acc[j] = __builtin_amdgcn_mfma_f32_16x16x32_bf16(ql[0], kh0, acc[j], 0,0,0);
        acc[j] = __builtin_amdgcn_mfma_f32_16x16x32_bf16(ql[1], kh1, acc[j], 0,0,0);
        acc[j] = __builtin_amdgcn_mfma_f32_16x16x32_bf16(qh[0], kl0, acc[j], 0,0,0);
        acc[j] = __builtin_amdgcn_mfma_f32_16x16x32_bf16(qh[1], kl1, acc[j], 0,0,0);
    }

    // scale + mask, scatter to LDS (C layout: row=quad*4+r, key=kw0+j*16+fr)
    const float* mrow = mask + b * S_;
    #pragma unroll
    for (int j=0;j<8;j++){
        float mv = mrow[kw0 + j*16 + fr];
        #pragma unroll
        for (int r=0;r<4;r++)
            sc[(quad*4 + r)*SCPAD + kw0 + j*16 + fr] = acc[j][r]*0.125f + mv;
    }
    __syncthreads();

    // wave w owns rows 4w..4w+3; lane l holds keys [8l, 8l+8) of each row
    float z[4][8];
    #pragma unroll
    for (int r=0;r<4;r++){
        const float* p = &sc[(wave*4 + r)*SCPAD + lane*8];
        float4 a = *(const float4*)p;
        float4 c = *(const float4*)(p + 4);
        z[r][0]=a.x; z[r][1]=a.y; z[r][2]=a.z; z[r][3]=a.w;
        z[r][4]=c.x; z[r][5]=c.y; z[r][6]=c.z; z[r][7]=c.w;
    }

    // per-row max (lockstep, 4 independent shfl chains)
    float tau[4];
    {
        float m[4];
        #pragma unroll
        for (int r=0;r<4;r++){
            float mm = z[r][0];
            #pragma unroll
            for (int i=1;i<8;i++) mm = fmaxf(mm, z[r][i]);
            m[r] = mm;
        }
        #pragma unroll
        for (int off=1; off<64; off<<=1){
            #pragma unroll
            for (int r=0;r<4;r++) m[r] = fmaxf(m[r], __shfl_xor(m[r], off, 64));
        }
        #pragma unroll
        for (int r=0;r<4;r++) tau[r] = m[r] - 1.0f;
    }

    // Michelot fixed-point, wave-local lockstep; exits on wave-uniform fixpoint
    for (int it=0; it<16; it++){
        float s[4], k[4];
        #pragma unroll
        for (int r=0;r<4;r++){
            float ss = 0.f, kk = 0.f;
            #pragma unroll
            for (int i=0;i<8;i++){
                float zz = z[r][i];
                if (zz > tau[r]){ ss += zz; kk += 1.f; }
            }
            s[r] = ss; k[r] = kk;
        }
        #pragma unroll
        for (int off=1; off<64; off<<=1){
            #pragma unroll
            for (int r=0;r<4;r++){
                s[r] += __shfl_xor(s[r], off, 64);
                k[r] += __shfl_xor(k[r], off, 64);
            }
        }
        bool any = false;
        #pragma unroll
        for (int r=0;r<4;r++){
            float tn = (s[r] - 1.0f) / k[r];
            any |= (tn != tau[r]);
            tau[r] = tn;
        }
        if (!any) break;
    }

    // ---- compact support into per-row LDS lists (reuse this wave's sc rows;
    //      wave-private, no barrier needed). Entry = p with key in low 9 bits.
    int ne[4];
    #pragma unroll
    for (int r=0;r<4;r++){
        float* list = &sc[(wave*4 + r)*SCPAD];
        float pv[8]; int kk[8]; unsigned cnt = 0;
        #pragma unroll
        for (int i=0;i<8;i++){
            float p = z[r][i] - tau[r];
            if (p > 0.f){ pv[cnt] = p; kk[cnt] = lane*8 + i; cnt++; }
        }
        unsigned inc = cnt;
        #pragma unroll
        for (int off=1; off<64; off<<=1){
            unsigned t = __shfl_up(inc, off, 64);
            inc += (lane >= off) ? t : 0u;
        }
        unsigned base = inc - cnt;
        for (unsigned j=0;j<cnt;j++){
            unsigned bits = (__float_as_uint(pv[j]) & ~511u) | (unsigned)kk[j];
            list[base + j] = __uint_as_float(bits);
        }
        ne[r] = (int)__shfl((int)inc, 63, 64);
    }

    // ---- PV: counted loop over support lists, 4 independent row-chains ----
    float ctx[4] = {0.f, 0.f, 0.f, 0.f};
    const float* vb = V + hb;
    int emax = max(max(ne[0], ne[1]), max(ne[2], ne[3]));
    for (int e=0; e<emax; e++){
        #pragma unroll
        for (int r=0;r<4;r++){
            if (e < ne[r]){
                float pk = sc[(wave*4 + r)*SCPAD + e];   // LDS broadcast
                int key = __float_as_uint(pk) & 511;
                ctx[r] += pk * vb[(size_t)key*DH_ + lane];
            }
        }
    }

    #pragma unroll
    for (int r=0;r<4;r++)
        out[((size_t)(b*S_ + q0 + wave*4 + r))*D_ + h*DH_ + lane] = ctx[r];
}

// ---------------------------------------------------------------------------
extern "C" void kernel_launch(void* const* d_in, const int* in_sizes, int n_in,
                              void* d_out, int out_size, void* d_ws, size_t ws_size,
                              hipStream_t stream) {
    const float* hs   = (const float*)d_in[0];
    const float* mask = (const float*)d_in[1];
    const float* Wq   = (const float*)d_in[2];
    const float* bq   = (const float*)d_in[3];
    const float* Wk   = (const float*)d_in[4];
    const float* bk   = (const float*)d_in[5];
    const float* Wv   = (const float*)d_in[6];
    const float* bv   = (const float*)d_in[7];
    float* out = (float*)d_out;

    const size_t per = (size_t)BH_ * S_ * DH_;   // 6291456
    char* w = (char*)d_ws;
    float*    vb  = (float*)w;    w += per*4;
    ushort_t* qhi = (ushort_t*)w; w += per*2;
    ushort_t* qlo = (ushort_t*)w; w += per*2;
    ushort_t* khi = (ushort_t*)w; w += per*2;
    ushort_t* klo = (ushort_t*)w; w += per*2;
    ushort_t* Xbf = (ushort_t*)w; w += per*2;
    ushort_t* Whi = (ushort_t*)w; w += (size_t)NTOT*D_*2;
    ushort_t* Wlo = (ushort_t*)w;

    convert_x<<<(int)(per/4/256), 256, 0, stream>>>(hs, Xbf, (int)(per/4));
    convert_w<<<dim3(D_*D_/4/256, 1, 3), 256, 0, stream>>>(Wq, Wk, Wv, Whi, Wlo);

    dim3 ggrid(NTOT/BN, MTOT/BM);   // (18, 64)
    gemm_split<<<ggrid, 256, 0, stream>>>(Xbf, Whi, Wlo, bq, bk, bv,
                                          qhi, qlo, khi, klo, vb);

    attn_mfma<<<BH_*32, 256, 0, stream>>>(qhi, qlo, khi, klo, vb, mask, out);
}

// Round 9
// 334.179 us; speedup vs baseline: 1.0575x; 1.0575x over previous
//
#include <hip/hip_runtime.h>
#include <math.h>

#define B_ 16
#define S_ 512
#define D_ 768
#define H_ 12
#define DH_ 64
#define BH_ (B_*H_)     // 192
#define MTOT (B_*S_)    // 8192
#define NTOT (3*D_)     // 2304

typedef unsigned short ushort_t;
typedef __attribute__((ext_vector_type(8))) short bf16x8;
typedef __attribute__((ext_vector_type(4))) float f32x4;

__device__ __forceinline__ unsigned short f2bf(float x){
    unsigned u = __float_as_uint(x);
    unsigned r = (u + 0x7FFFu + ((u >> 16) & 1u)) >> 16;
    return (unsigned short)r;
}
__device__ __forceinline__ float bf2f(unsigned short b){
    return __uint_as_float(((unsigned)b) << 16);
}

__device__ __forceinline__ void cp16(const void* g, void* l){
    __builtin_amdgcn_global_load_lds(
        (const __attribute__((address_space(1))) unsigned int*)g,
        (__attribute__((address_space(3))) unsigned int*)l, 16, 0, 0);
}

// ---------------------------------------------------------------------------
// f32 -> single bf16 (round-to-nearest), 4 elems/thread
// ---------------------------------------------------------------------------
__global__ __launch_bounds__(256)
void convert_x(const float* __restrict__ src, ushort_t* __restrict__ dst, int n4)
{
    int i = blockIdx.x * 256 + threadIdx.x;
    if (i >= n4) return;
    float4 x = ((const float4*)src)[i];
    union { ushort_t u[4]; uint2 v; } p;
    p.u[0] = f2bf(x.x); p.u[1] = f2bf(x.y);
    p.u[2] = f2bf(x.z); p.u[3] = f2bf(x.w);
    ((uint2*)dst)[i] = p.v;
}

// weights: split hi/lo, all three matrices in one launch
__global__ __launch_bounds__(256)
void convert_w(const float* __restrict__ Wq, const float* __restrict__ Wk,
               const float* __restrict__ Wv, ushort_t* __restrict__ hi,
               ushort_t* __restrict__ lo)
{
    const float* src = (blockIdx.z==0) ? Wq : (blockIdx.z==1) ? Wk : Wv;
    const int n4 = D_*D_/4;
    int i = blockIdx.x * 256 + threadIdx.x;
    if (i >= n4) return;
    size_t off4 = (size_t)blockIdx.z * n4;
    float4 x = ((const float4*)src)[i];
    union { ushort_t u[4]; uint2 v; } ph, pl;
    float xs[4] = {x.x, x.y, x.z, x.w};
    #pragma unroll
    for (int c = 0; c < 4; c++){
        unsigned short h = f2bf(xs[c]);
        ph.u[c] = h;
        pl.u[c] = f2bf(xs[c] - bf2f(h));
    }
    ((uint2*)hi)[off4 + i] = ph.v;
    ((uint2*)lo)[off4 + i] = pl.v;
}

// ---------------------------------------------------------------------------
// MFMA GEMM: C[m,n] = sum_k Xbf[m,k] * W[n,k] + bias; X single bf16, W hi/lo
// (2 MFMAs per tile-pair). mat 0 -> Q hi/lo, 1 -> K hi/lo, 2 -> V f32.
// ---------------------------------------------------------------------------
#define BM 128
#define BN 128
#define BK 32

__global__ __launch_bounds__(256)
void gemm_split(const ushort_t* __restrict__ A,
                const ushort_t* __restrict__ Bhi, const ushort_t* __restrict__ Blo,
                const float* __restrict__ bq, const float* __restrict__ bk,
                const float* __restrict__ bv,
                ushort_t* __restrict__ qhi, ushort_t* __restrict__ qlo,
                ushort_t* __restrict__ khi, ushort_t* __restrict__ klo,
                float* __restrict__ outv)
{
    __shared__ ushort_t Ah[BM*BK], Bh[BN*BK], Bl[BN*BK];  // 24 KB

    const int tid  = threadIdx.x;
    const int lane = tid & 63, wave = tid >> 6;
    const int m0 = blockIdx.y * BM, n0 = blockIdx.x * BN;
    const int wm = (wave >> 1) * 64, wn = (wave & 1) * 64;

    f32x4 acc[4][4];
    #pragma unroll
    for (int i=0;i<4;i++)
        #pragma unroll
        for (int j=0;j<4;j++) acc[i][j] = (f32x4){0.f,0.f,0.f,0.f};

    const int r0 = tid >> 2, c0 = (tid & 3) * 8;
    const size_t ga0 = (size_t)(m0 + r0)      * D_ + c0;
    const size_t ga1 = (size_t)(m0 + 64 + r0) * D_ + c0;
    const size_t gb0 = (size_t)(n0 + r0)      * D_ + c0;
    const size_t gb1 = (size_t)(n0 + 64 + r0) * D_ + c0;
    const int l0 = wave * 512;
    const int l1 = 2048 + wave * 512;

    const int fr = lane & 15, kc = (lane >> 4) * 8;

    for (int k0 = 0; k0 < D_; k0 += BK) {
        cp16(A   + ga0 + k0, Ah + l0);
        cp16(A   + ga1 + k0, Ah + l1);
        cp16(Bhi + gb0 + k0, Bh + l0);
        cp16(Bhi + gb1 + k0, Bh + l1);
        cp16(Blo + gb0 + k0, Bl + l0);
        cp16(Blo + gb1 + k0, Bl + l1);
        __syncthreads();

        bf16x8 fa[4], fbh[4], fbl[4];
        #pragma unroll
        for (int i = 0; i < 4; i++){
            fa[i]  = *(const bf16x8*)&Ah[(wm + i*16 + fr)*BK + kc];
            fbh[i] = *(const bf16x8*)&Bh[(wn + i*16 + fr)*BK + kc];
            fbl[i] = *(const bf16x8*)&Bl[(wn + i*16 + fr)*BK + kc];
        }
        #pragma unroll
        for (int i = 0; i < 4; i++)
            #pragma unroll
            for (int j = 0; j < 4; j++){
                acc[i][j] = __builtin_amdgcn_mfma_f32_16x16x32_bf16(fa[i], fbh[j], acc[i][j], 0,0,0);
                acc[i][j] = __builtin_amdgcn_mfma_f32_16x16x32_bf16(fa[i], fbl[j], acc[i][j], 0,0,0);
            }
        __syncthreads();
    }

    const int mat = n0 / D_;   // block-uniform
    const float* bias = (mat==0) ? bq : (mat==1) ? bk : bv;
    const int col = lane & 15, rbase = (lane >> 4) * 4;
    #pragma unroll
    for (int j = 0; j < 4; j++){
        int nn = n0 + wn + j*16 + col - mat*D_;
        int h = nn >> 6, d = nn & 63;
        float bsv = bias[nn];
        #pragma unroll
        for (int i = 0; i < 4; i++){
            #pragma unroll
            for (int r = 0; r < 4; r++){
                int m = m0 + wm + i*16 + rbase + r;
                int bb = m >> 9, s = m & 511;
                size_t idx = (((size_t)bb*H_ + h)*S_ + s)*DH_ + d;
                float val = acc[i][j][r] + bsv;
                if (mat == 2) outv[idx] = val;
                else {
                    ushort_t hv = f2bf(val);
                    ushort_t lv = f2bf(val - bf2f(hv));
                    if (mat == 0){ qhi[idx] = hv; qlo[idx] = lv; }
                    else         { khi[idx] = hv; klo[idx] = lv; }
                }
            }
        }
    }
}

// ---------------------------------------------------------------------------
// MFMA sparsemax attention. Phase 1: wave w computes scores for 16 rows x
// keys [128w,128w+128) -> LDS (K tiles ring-prefetched depth 2). Phase 2:
// wave w owns rows 4w..4w+3 fully: wave-local Michelot tau, then PV via
// ballot-sparse gather with the 4 row-chains INTERLEAVED (4 independent
// V loads in flight per pass). Direct store. One barrier total.
// ---------------------------------------------------------------------------
#define SCPAD 524   // float stride; spreads banks across rows

struct KTile { bf16x8 h0, h1, l0, l1; };

__global__ __launch_bounds__(256)
void attn_mfma(const ushort_t* __restrict__ Qhi, const ushort_t* __restrict__ Qlo,
               const ushort_t* __restrict__ Khi, const ushort_t* __restrict__ Klo,
               const float* __restrict__ V, const float* __restrict__ mask,
               float* __restrict__ out)
{
    __shared__ float sc[16*SCPAD];   // 33.5 KB scores [row][key]

    const int lane = threadIdx.x & 63;
    const int wave = threadIdx.x >> 6;
    const int fr = lane & 15, quad = lane >> 4;
    const int bh = blockIdx.x >> 5;            // same-head blocks adjacent
    const int q0 = (blockIdx.x & 31) * 16;
    const int b = bh / H_, h = bh % H_;
    const size_t hb = (size_t)bh * S_ * DH_;
    const int kw0 = wave * 128;                // phase-1 key range

    // Q A-fragments: row = fr (q0+fr), k = quad*8 + [0..8)
    bf16x8 qh[2], ql[2];
    {
        const ushort_t* qp  = Qhi + hb + (size_t)(q0 + fr)*DH_ + quad*8;
        const ushort_t* qp2 = Qlo + hb + (size_t)(q0 + fr)*DH_ + quad*8;
        qh[0] = *(const bf16x8*)qp;   qh[1] = *(const bf16x8*)(qp + 32);
        ql[0] = *(const bf16x8*)qp2;  ql[1] = *(const bf16x8*)(qp2 + 32);
    }

    const ushort_t* kbh = Khi + hb + (size_t)(kw0 + fr)*DH_ + quad*8;
    const ushort_t* kbl = Klo + hb + (size_t)(kw0 + fr)*DH_ + quad*8;
    #define LOADK(dst, j) do { \
        (dst).h0 = *(const bf16x8*)(kbh + (size_t)(j)*16*DH_); \
        (dst).h1 = *(const bf16x8*)(kbh + (size_t)(j)*16*DH_ + 32); \
        (dst).l0 = *(const bf16x8*)(kbl + (size_t)(j)*16*DH_); \
        (dst).l1 = *(const bf16x8*)(kbl + (size_t)(j)*16*DH_ + 32); \
    } while(0)

    f32x4 acc[8];
    #pragma unroll
    for (int j=0;j<8;j++) acc[j] = (f32x4){0.f,0.f,0.f,0.f};

    KTile buf[3];
    LOADK(buf[0], 0);
    LOADK(buf[1], 1);
    #pragma unroll
    for (int j=0;j<8;j++){
        if (j+2 < 8) LOADK(buf[(j+2)%3], j+2);
        KTile& t = buf[j%3];
        acc[j] = __builtin_amdgcn_mfma_f32_16x16x32_bf16(qh[0], t.h0, acc[j], 0,0,0);
        acc[j] = __builtin_amdgcn_mfma_f32_16x16x32_bf16(qh[1], t.h1, acc[j], 0,0,0);
        acc[j] = __builtin_amdgcn_mfma_f32_16x16x32_bf16(ql[0], t.h0, acc[j], 0,0,0);
        acc[j] = __builtin_amdgcn_mfma_f32_16x16x32_bf16(ql[1], t.h1, acc[j], 0,0,0);
        acc[j] = __builtin_amdgcn_mfma_f32_16x16x32_bf16(qh[0], t.l0, acc[j], 0,0,0);
        acc[j] = __builtin_amdgcn_mfma_f32_16x16x32_bf16(qh[1], t.l1, acc[j], 0,0,0);
    }

    // scale + mask, scatter to LDS (C layout: row=quad*4+r, key=kw0+j*16+fr)
    const float* mrow = mask + b * S_;
    #pragma unroll
    for (int j=0;j<8;j++){
        float mv = mrow[kw0 + j*16 + fr];
        #pragma unroll
        for (int r=0;r<4;r++)
            sc[(quad*4 + r)*SCPAD + kw0 + j*16 + fr] = acc[j][r]*0.125f + mv;
    }
    __syncthreads();

    // wave w owns rows 4w..4w+3; lane l holds keys [8l, 8l+8) of each row
    float z[4][8];
    #pragma unroll
    for (int r=0;r<4;r++){
        const float* p = &sc[(wave*4 + r)*SCPAD + lane*8];
        float4 a = *(const float4*)p;
        float4 c = *(const float4*)(p + 4);
        z[r][0]=a.x; z[r][1]=a.y; z[r][2]=a.z; z[r][3]=a.w;
        z[r][4]=c.x; z[r][5]=c.y; z[r][6]=c.z; z[r][7]=c.w;
    }

    // per-row max (lockstep, 4 independent shfl chains)
    float tau[4];
    {
        float m[4];
        #pragma unroll
        for (int r=0;r<4;r++){
            float mm = z[r][0];
            #pragma unroll
            for (int i=1;i<8;i++) mm = fmaxf(mm, z[r][i]);
            m[r] = mm;
        }
        #pragma unroll
        for (int off=1; off<64; off<<=1){
            #pragma unroll
            for (int r=0;r<4;r++) m[r] = fmaxf(m[r], __shfl_xor(m[r], off, 64));
        }
        #pragma unroll
        for (int r=0;r<4;r++) tau[r] = m[r] - 1.0f;
    }

    // Michelot fixed-point, wave-local lockstep; exits on wave-uniform fixpoint
    for (int it=0; it<16; it++){
        float s[4], k[4];
        #pragma unroll
        for (int r=0;r<4;r++){
            float ss = 0.f, kk = 0.f;
            #pragma unroll
            for (int i=0;i<8;i++){
                float zz = z[r][i];
                if (zz > tau[r]){ ss += zz; kk += 1.f; }
            }
            s[r] = ss; k[r] = kk;
        }
        #pragma unroll
        for (int off=1; off<64; off<<=1){
            #pragma unroll
            for (int r=0;r<4;r++){
                s[r] += __shfl_xor(s[r], off, 64);
                k[r] += __shfl_xor(k[r], off, 64);
            }
        }
        bool any = false;
        #pragma unroll
        for (int r=0;r<4;r++){
            float tn = (s[r] - 1.0f) / k[r];
            any |= (tn != tau[r]);
            tau[r] = tn;
        }
        if (!any) break;
    }

    // PV: ballot-sparse gather, 4 row-chains interleaved per pass.
    // key = 8*src + i; V row reads coalesced (256B). Masks are wave-uniform
    // so all branches are scalar; 4 loads per pass are independent.
    float ctx[4] = {0.f, 0.f, 0.f, 0.f};
    const float* vb = V + hb;
    #pragma unroll
    for (int i=0;i<8;i++){
        float p0 = z[0][i] - tau[0];
        float p1 = z[1][i] - tau[1];
        float p2 = z[2][i] - tau[2];
        float p3 = z[3][i] - tau[3];
        unsigned long long m0 = __ballot(p0 > 0.f);
        unsigned long long m1 = __ballot(p1 > 0.f);
        unsigned long long m2 = __ballot(p2 > 0.f);
        unsigned long long m3 = __ballot(p3 > 0.f);
        while (m0 | m1 | m2 | m3){
            if (m0){ int s = __ffsll((long long)m0) - 1; m0 &= m0 - 1;
                     ctx[0] += __shfl(p0, s, 64) * vb[(size_t)(s*8 + i)*DH_ + lane]; }
            if (m1){ int s = __ffsll((long long)m1) - 1; m1 &= m1 - 1;
                     ctx[1] += __shfl(p1, s, 64) * vb[(size_t)(s*8 + i)*DH_ + lane]; }
            if (m2){ int s = __ffsll((long long)m2) - 1; m2 &= m2 - 1;
                     ctx[2] += __shfl(p2, s, 64) * vb[(size_t)(s*8 + i)*DH_ + lane]; }
            if (m3){ int s = __ffsll((long long)m3) - 1; m3 &= m3 - 1;
                     ctx[3] += __shfl(p3, s, 64) * vb[(size_t)(s*8 + i)*DH_ + lane]; }
        }
    }

    #pragma unroll
    for (int r=0;r<4;r++)
        out[((size_t)(b*S_ + q0 + wave*4 + r))*D_ + h*DH_ + lane] = ctx[r];
}

// ---------------------------------------------------------------------------
extern "C" void kernel_launch(void* const* d_in, const int* in_sizes, int n_in,
                              void* d_out, int out_size, void* d_ws, size_t ws_size,
                              hipStream_t stream) {
    const float* hs   = (const float*)d_in[0];
    const float* mask = (const float*)d_in[1];
    const float* Wq   = (const float*)d_in[2];
    const float* bq   = (const float*)d_in[3];
    const float* Wk   = (const float*)d_in[4];
    const float* bk   = (const float*)d_in[5];
    const float* Wv   = (const float*)d_in[6];
    const float* bv   = (const float*)d_in[7];
    float* out = (float*)d_out;

    const size_t per = (size_t)BH_ * S_ * DH_;   // 6291456
    char* w = (char*)d_ws;
    float*    vb  = (float*)w;    w += per*4;
    ushort_t* qhi = (ushort_t*)w; w += per*2;
    ushort_t* qlo = (ushort_t*)w; w += per*2;
    ushort_t* khi = (ushort_t*)w; w += per*2;
    ushort_t* klo = (ushort_t*)w; w += per*2;
    ushort_t* Xbf = (ushort_t*)w; w += per*2;
    ushort_t* Whi = (ushort_t*)w; w += (size_t)NTOT*D_*2;
    ushort_t* Wlo = (ushort_t*)w;

    convert_x<<<(int)(per/4/256), 256, 0, stream>>>(hs, Xbf, (int)(per/4));
    convert_w<<<dim3(D_*D_/4/256, 1, 3), 256, 0, stream>>>(Wq, Wk, Wv, Whi, Wlo);

    dim3 ggrid(NTOT/BN, MTOT/BM);   // (18, 64)
    gemm_split<<<ggrid, 256, 0, stream>>>(Xbf, Whi, Wlo, bq, bk, bv,
                                          qhi, qlo, khi, klo, vb);

    attn_mfma<<<BH_*32, 256, 0, stream>>>(qhi, qlo, khi, klo, vb, mask, out);
}

// Round 10
// 329.069 us; speedup vs baseline: 1.0739x; 1.0155x over previous
//
#include <hip/hip_runtime.h>
#include <math.h>

#define B_ 16
#define S_ 512
#define D_ 768
#define H_ 12
#define DH_ 64
#define BH_ (B_*H_)     // 192
#define MTOT (B_*S_)    // 8192
#define NTOT (3*D_)     // 2304

typedef unsigned short ushort_t;
typedef __attribute__((ext_vector_type(8))) short bf16x8;
typedef __attribute__((ext_vector_type(4))) float f32x4;

__device__ __forceinline__ unsigned short f2bf(float x){
    unsigned u = __float_as_uint(x);
    unsigned r = (u + 0x7FFFu + ((u >> 16) & 1u)) >> 16;
    return (unsigned short)r;
}
__device__ __forceinline__ float bf2f(unsigned short b){
    return __uint_as_float(((unsigned)b) << 16);
}

__device__ __forceinline__ void cp16(const void* g, void* l){
    __builtin_amdgcn_global_load_lds(
        (const __attribute__((address_space(1))) unsigned int*)g,
        (__attribute__((address_space(3))) unsigned int*)l, 16, 0, 0);
}

// ---------------------------------------------------------------------------
// f32 -> single bf16 (round-to-nearest), 4 elems/thread
// ---------------------------------------------------------------------------
__global__ __launch_bounds__(256)
void convert_x(const float* __restrict__ src, ushort_t* __restrict__ dst, int n4)
{
    int i = blockIdx.x * 256 + threadIdx.x;
    if (i >= n4) return;
    float4 x = ((const float4*)src)[i];
    union { ushort_t u[4]; uint2 v; } p;
    p.u[0] = f2bf(x.x); p.u[1] = f2bf(x.y);
    p.u[2] = f2bf(x.z); p.u[3] = f2bf(x.w);
    ((uint2*)dst)[i] = p.v;
}

// weights: split hi/lo, all three matrices in one launch
__global__ __launch_bounds__(256)
void convert_w(const float* __restrict__ Wq, const float* __restrict__ Wk,
               const float* __restrict__ Wv, ushort_t* __restrict__ hi,
               ushort_t* __restrict__ lo)
{
    const float* src = (blockIdx.z==0) ? Wq : (blockIdx.z==1) ? Wk : Wv;
    const int n4 = D_*D_/4;
    int i = blockIdx.x * 256 + threadIdx.x;
    if (i >= n4) return;
    size_t off4 = (size_t)blockIdx.z * n4;
    float4 x = ((const float4*)src)[i];
    union { ushort_t u[4]; uint2 v; } ph, pl;
    float xs[4] = {x.x, x.y, x.z, x.w};
    #pragma unroll
    for (int c = 0; c < 4; c++){
        unsigned short h = f2bf(xs[c]);
        ph.u[c] = h;
        pl.u[c] = f2bf(xs[c] - bf2f(h));
    }
    ((uint2*)hi)[off4 + i] = ph.v;
    ((uint2*)lo)[off4 + i] = pl.v;
}

// ---------------------------------------------------------------------------
// MFMA GEMM: C[m,n] = sum_k Xbf[m,k] * W[n,k] + bias; X single bf16, W hi/lo
// (2 MFMAs per tile-pair). mat 0 -> Q hi/lo, 1 -> K hi/lo, 2 -> V f32.
// ---------------------------------------------------------------------------
#define BM 128
#define BN 128
#define BK 32

__global__ __launch_bounds__(256)
void gemm_split(const ushort_t* __restrict__ A,
                const ushort_t* __restrict__ Bhi, const ushort_t* __restrict__ Blo,
                const float* __restrict__ bq, const float* __restrict__ bk,
                const float* __restrict__ bv,
                ushort_t* __restrict__ qhi, ushort_t* __restrict__ qlo,
                ushort_t* __restrict__ khi, ushort_t* __restrict__ klo,
                float* __restrict__ outv)
{
    __shared__ ushort_t Ah[BM*BK], Bh[BN*BK], Bl[BN*BK];  // 24 KB

    const int tid  = threadIdx.x;
    const int lane = tid & 63, wave = tid >> 6;
    const int m0 = blockIdx.y * BM, n0 = blockIdx.x * BN;
    const int wm = (wave >> 1) * 64, wn = (wave & 1) * 64;

    f32x4 acc[4][4];
    #pragma unroll
    for (int i=0;i<4;i++)
        #pragma unroll
        for (int j=0;j<4;j++) acc[i][j] = (f32x4){0.f,0.f,0.f,0.f};

    const int r0 = tid >> 2, c0 = (tid & 3) * 8;
    const size_t ga0 = (size_t)(m0 + r0)      * D_ + c0;
    const size_t ga1 = (size_t)(m0 + 64 + r0) * D_ + c0;
    const size_t gb0 = (size_t)(n0 + r0)      * D_ + c0;
    const size_t gb1 = (size_t)(n0 + 64 + r0) * D_ + c0;
    const int l0 = wave * 512;
    const int l1 = 2048 + wave * 512;

    const int fr = lane & 15, kc = (lane >> 4) * 8;

    for (int k0 = 0; k0 < D_; k0 += BK) {
        cp16(A   + ga0 + k0, Ah + l0);
        cp16(A   + ga1 + k0, Ah + l1);
        cp16(Bhi + gb0 + k0, Bh + l0);
        cp16(Bhi + gb1 + k0, Bh + l1);
        cp16(Blo + gb0 + k0, Bl + l0);
        cp16(Blo + gb1 + k0, Bl + l1);
        __syncthreads();

        bf16x8 fa[4], fbh[4], fbl[4];
        #pragma unroll
        for (int i = 0; i < 4; i++){
            fa[i]  = *(const bf16x8*)&Ah[(wm + i*16 + fr)*BK + kc];
            fbh[i] = *(const bf16x8*)&Bh[(wn + i*16 + fr)*BK + kc];
            fbl[i] = *(const bf16x8*)&Bl[(wn + i*16 + fr)*BK + kc];
        }
        #pragma unroll
        for (int i = 0; i < 4; i++)
            #pragma unroll
            for (int j = 0; j < 4; j++){
                acc[i][j] = __builtin_amdgcn_mfma_f32_16x16x32_bf16(fa[i], fbh[j], acc[i][j], 0,0,0);
                acc[i][j] = __builtin_amdgcn_mfma_f32_16x16x32_bf16(fa[i], fbl[j], acc[i][j], 0,0,0);
            }
        __syncthreads();
    }

    const int mat = n0 / D_;   // block-uniform
    const float* bias = (mat==0) ? bq : (mat==1) ? bk : bv;
    const int col = lane & 15, rbase = (lane >> 4) * 4;
    #pragma unroll
    for (int j = 0; j < 4; j++){
        int nn = n0 + wn + j*16 + col - mat*D_;
        int h = nn >> 6, d = nn & 63;
        float bsv = bias[nn];
        #pragma unroll
        for (int i = 0; i < 4; i++){
            #pragma unroll
            for (int r = 0; r < 4; r++){
                int m = m0 + wm + i*16 + rbase + r;
                int bb = m >> 9, s = m & 511;
                size_t idx = (((size_t)bb*H_ + h)*S_ + s)*DH_ + d;
                float val = acc[i][j][r] + bsv;
                if (mat == 2) outv[idx] = val;
                else {
                    ushort_t hv = f2bf(val);
                    ushort_t lv = f2bf(val - bf2f(hv));
                    if (mat == 0){ qhi[idx] = hv; qlo[idx] = lv; }
                    else         { khi[idx] = hv; klo[idx] = lv; }
                }
            }
        }
    }
}

// ---------------------------------------------------------------------------
// MFMA sparsemax attention, 8-wave blocks for occupancy.
// Block = (head, 16 q-rows), 512 threads. Phase 1: wave w computes scores
// for 16 rows x keys [64w,64w+64) -> LDS (acc[4], 24 MFMAs). Phase 2: wave w
// owns rows 2w..2w+1 fully: wave-local Michelot tau + ballot-sparse PV with
// 2 rows x 2 i-chunks interleaved (4 loads in flight). One barrier total.
// ---------------------------------------------------------------------------
#define SCPAD 524   // float stride; spreads banks across rows

__global__ __launch_bounds__(512)
void attn_mfma(const ushort_t* __restrict__ Qhi, const ushort_t* __restrict__ Qlo,
               const ushort_t* __restrict__ Khi, const ushort_t* __restrict__ Klo,
               const float* __restrict__ V, const float* __restrict__ mask,
               float* __restrict__ out)
{
    __shared__ float sc[16*SCPAD];   // 33.5 KB scores [row][key]

    const int lane = threadIdx.x & 63;
    const int wave = threadIdx.x >> 6;         // 0..7
    const int fr = lane & 15, quad = lane >> 4;
    const int bh = blockIdx.x >> 5;            // same-head blocks adjacent
    const int q0 = (blockIdx.x & 31) * 16;
    const int b = bh / H_, h = bh % H_;
    const size_t hb = (size_t)bh * S_ * DH_;
    const int kw0 = wave * 64;                 // phase-1 key range (64 keys)

    // Q A-fragments: row = fr (q0+fr), k = quad*8 + [0..8)
    bf16x8 qh[2], ql[2];
    {
        const ushort_t* qp  = Qhi + hb + (size_t)(q0 + fr)*DH_ + quad*8;
        const ushort_t* qp2 = Qlo + hb + (size_t)(q0 + fr)*DH_ + quad*8;
        qh[0] = *(const bf16x8*)qp;   qh[1] = *(const bf16x8*)(qp + 32);
        ql[0] = *(const bf16x8*)qp2;  ql[1] = *(const bf16x8*)(qp2 + 32);
    }

    f32x4 acc[4];
    #pragma unroll
    for (int j=0;j<4;j++) acc[j] = (f32x4){0.f,0.f,0.f,0.f};

    #pragma unroll
    for (int j=0;j<4;j++){
        const ushort_t* kp  = Khi + hb + (size_t)(kw0 + j*16 + fr)*DH_ + quad*8;
        const ushort_t* kp2 = Klo + hb + (size_t)(kw0 + j*16 + fr)*DH_ + quad*8;
        bf16x8 kh0 = *(const bf16x8*)kp;
        bf16x8 kh1 = *(const bf16x8*)(kp + 32);
        bf16x8 kl0 = *(const bf16x8*)kp2;
        bf16x8 kl1 = *(const bf16x8*)(kp2 + 32);
        acc[j] = __builtin_amdgcn_mfma_f32_16x16x32_bf16(qh[0], kh0, acc[j], 0,0,0);
        acc[j] = __builtin_amdgcn_mfma_f32_16x16x32_bf16(qh[1], kh1, acc[j], 0,0,0);
        acc[j] = __builtin_amdgcn_mfma_f32_16x16x32_bf16(ql[0], kh0, acc[j], 0,0,0);
        acc[j] = __builtin_amdgcn_mfma_f32_16x16x32_bf16(ql[1], kh1, acc[j], 0,0,0);
        acc[j] = __builtin_amdgcn_mfma_f32_16x16x32_bf16(qh[0], kl0, acc[j], 0,0,0);
        acc[j] = __builtin_amdgcn_mfma_f32_16x16x32_bf16(qh[1], kl1, acc[j], 0,0,0);
    }

    // scale + mask, scatter to LDS (C layout: row=quad*4+r, key=kw0+j*16+fr)
    const float* mrow = mask + b * S_;
    #pragma unroll
    for (int j=0;j<4;j++){
        float mv = mrow[kw0 + j*16 + fr];
        #pragma unroll
        for (int r=0;r<4;r++)
            sc[(quad*4 + r)*SCPAD + kw0 + j*16 + fr] = acc[j][r]*0.125f + mv;
    }
    __syncthreads();

    // wave w owns rows 2w, 2w+1; lane l holds keys [8l, 8l+8) of each row
    float z[2][8];
    #pragma unroll
    for (int r=0;r<2;r++){
        const float* p = &sc[(wave*2 + r)*SCPAD + lane*8];
        float4 a = *(const float4*)p;
        float4 c = *(const float4*)(p + 4);
        z[r][0]=a.x; z[r][1]=a.y; z[r][2]=a.z; z[r][3]=a.w;
        z[r][4]=c.x; z[r][5]=c.y; z[r][6]=c.z; z[r][7]=c.w;
    }

    // per-row max (lockstep, 2 independent shfl chains)
    float tau[2];
    {
        float m[2];
        #pragma unroll
        for (int r=0;r<2;r++){
            float mm = z[r][0];
            #pragma unroll
            for (int i=1;i<8;i++) mm = fmaxf(mm, z[r][i]);
            m[r] = mm;
        }
        #pragma unroll
        for (int off=1; off<64; off<<=1){
            #pragma unroll
            for (int r=0;r<2;r++) m[r] = fmaxf(m[r], __shfl_xor(m[r], off, 64));
        }
        #pragma unroll
        for (int r=0;r<2;r++) tau[r] = m[r] - 1.0f;
    }

    // Michelot fixed-point, wave-local lockstep; exits on wave-uniform fixpoint
    for (int it=0; it<16; it++){
        float s[2], k[2];
        #pragma unroll
        for (int r=0;r<2;r++){
            float ss = 0.f, kk = 0.f;
            #pragma unroll
            for (int i=0;i<8;i++){
                float zz = z[r][i];
                if (zz > tau[r]){ ss += zz; kk += 1.f; }
            }
            s[r] = ss; k[r] = kk;
        }
        #pragma unroll
        for (int off=1; off<64; off<<=1){
            #pragma unroll
            for (int r=0;r<2;r++){
                s[r] += __shfl_xor(s[r], off, 64);
                k[r] += __shfl_xor(k[r], off, 64);
            }
        }
        bool any = false;
        #pragma unroll
        for (int r=0;r<2;r++){
            float tn = (s[r] - 1.0f) / k[r];
            any |= (tn != tau[r]);
            tau[r] = tn;
        }
        if (!any) break;
    }

    // PV: ballot-sparse gather, 2 rows x 2 i-chunks interleaved per pass
    // (4 independent V loads in flight). key = 8*src + i; 256B coalesced.
    float ctx[2] = {0.f, 0.f};
    const float* vb = V + hb;
    #pragma unroll
    for (int i=0;i<8;i+=2){
        float p00 = z[0][i]   - tau[0];
        float p01 = z[0][i+1] - tau[0];
        float p10 = z[1][i]   - tau[1];
        float p11 = z[1][i+1] - tau[1];
        unsigned long long m00 = __ballot(p00 > 0.f);
        unsigned long long m01 = __ballot(p01 > 0.f);
        unsigned long long m10 = __ballot(p10 > 0.f);
        unsigned long long m11 = __ballot(p11 > 0.f);
        while (m00 | m01 | m10 | m11){
            if (m00){ int s = __ffsll((long long)m00) - 1; m00 &= m00 - 1;
                      ctx[0] += __shfl(p00, s, 64) * vb[(size_t)(s*8 + i)*DH_ + lane]; }
            if (m01){ int s = __ffsll((long long)m01) - 1; m01 &= m01 - 1;
                      ctx[0] += __shfl(p01, s, 64) * vb[(size_t)(s*8 + i+1)*DH_ + lane]; }
            if (m10){ int s = __ffsll((long long)m10) - 1; m10 &= m10 - 1;
                      ctx[1] += __shfl(p10, s, 64) * vb[(size_t)(s*8 + i)*DH_ + lane]; }
            if (m11){ int s = __ffsll((long long)m11) - 1; m11 &= m11 - 1;
                      ctx[1] += __shfl(p11, s, 64) * vb[(size_t)(s*8 + i+1)*DH_ + lane]; }
        }
    }

    #pragma unroll
    for (int r=0;r<2;r++)
        out[((size_t)(b*S_ + q0 + wave*2 + r))*D_ + h*DH_ + lane] = ctx[r];
}

// ---------------------------------------------------------------------------
extern "C" void kernel_launch(void* const* d_in, const int* in_sizes, int n_in,
                              void* d_out, int out_size, void* d_ws, size_t ws_size,
                              hipStream_t stream) {
    const float* hs   = (const float*)d_in[0];
    const float* mask = (const float*)d_in[1];
    const float* Wq   = (const float*)d_in[2];
    const float* bq   = (const float*)d_in[3];
    const float* Wk   = (const float*)d_in[4];
    const float* bk   = (const float*)d_in[5];
    const float* Wv   = (const float*)d_in[6];
    const float* bv   = (const float*)d_in[7];
    float* out = (float*)d_out;

    const size_t per = (size_t)BH_ * S_ * DH_;   // 6291456
    char* w = (char*)d_ws;
    float*    vb  = (float*)w;    w += per*4;
    ushort_t* qhi = (ushort_t*)w; w += per*2;
    ushort_t* qlo = (ushort_t*)w; w += per*2;
    ushort_t* khi = (ushort_t*)w; w += per*2;
    ushort_t* klo = (ushort_t*)w; w += per*2;
    ushort_t* Xbf = (ushort_t*)w; w += per*2;
    ushort_t* Whi = (ushort_t*)w; w += (size_t)NTOT*D_*2;
    ushort_t* Wlo = (ushort_t*)w;

    convert_x<<<(int)(per/4/256), 256, 0, stream>>>(hs, Xbf, (int)(per/4));
    convert_w<<<dim3(D_*D_/4/256, 1, 3), 256, 0, stream>>>(Wq, Wk, Wv, Whi, Wlo);

    dim3 ggrid(NTOT/BN, MTOT/BM);   // (18, 64)
    gemm_split<<<ggrid, 256, 0, stream>>>(Xbf, Whi, Wlo, bq, bk, bv,
                                          qhi, qlo, khi, klo, vb);

    attn_mfma<<<BH_*32, 512, 0, stream>>>(qhi, qlo, khi, klo, vb, mask, out);
}

// Round 11
// 321.436 us; speedup vs baseline: 1.0994x; 1.0237x over previous
//
#include <hip/hip_runtime.h>
#include <math.h>

#define B_ 16
#define S_ 512
#define D_ 768
#define H_ 12
#define DH_ 64
#define BH_ (B_*H_)     // 192
#define MTOT (B_*S_)    // 8192
#define NTOT (3*D_)     // 2304

typedef unsigned short ushort_t;
typedef __attribute__((ext_vector_type(8))) short bf16x8;
typedef __attribute__((ext_vector_type(4))) float f32x4;

__device__ __forceinline__ unsigned short f2bf(float x){
    unsigned u = __float_as_uint(x);
    unsigned r = (u + 0x7FFFu + ((u >> 16) & 1u)) >> 16;
    return (unsigned short)r;
}
__device__ __forceinline__ float bf2f(unsigned short b){
    return __uint_as_float(((unsigned)b) << 16);
}

__device__ __forceinline__ void cp16(const void* g, void* l){
    __builtin_amdgcn_global_load_lds(
        (const __attribute__((address_space(1))) unsigned int*)g,
        (__attribute__((address_space(3))) unsigned int*)l, 16, 0, 0);
}

// ---------------------------------------------------------------------------
// f32 -> single bf16 (round-to-nearest), 4 elems/thread
// ---------------------------------------------------------------------------
__global__ __launch_bounds__(256)
void convert_x(const float* __restrict__ src, ushort_t* __restrict__ dst, int n4)
{
    int i = blockIdx.x * 256 + threadIdx.x;
    if (i >= n4) return;
    float4 x = ((const float4*)src)[i];
    union { ushort_t u[4]; uint2 v; } p;
    p.u[0] = f2bf(x.x); p.u[1] = f2bf(x.y);
    p.u[2] = f2bf(x.z); p.u[3] = f2bf(x.w);
    ((uint2*)dst)[i] = p.v;
}

// weights: split hi/lo, all three matrices in one launch
__global__ __launch_bounds__(256)
void convert_w(const float* __restrict__ Wq, const float* __restrict__ Wk,
               const float* __restrict__ Wv, ushort_t* __restrict__ hi,
               ushort_t* __restrict__ lo)
{
    const float* src = (blockIdx.z==0) ? Wq : (blockIdx.z==1) ? Wk : Wv;
    const int n4 = D_*D_/4;
    int i = blockIdx.x * 256 + threadIdx.x;
    if (i >= n4) return;
    size_t off4 = (size_t)blockIdx.z * n4;
    float4 x = ((const float4*)src)[i];
    union { ushort_t u[4]; uint2 v; } ph, pl;
    float xs[4] = {x.x, x.y, x.z, x.w};
    #pragma unroll
    for (int c = 0; c < 4; c++){
        unsigned short h = f2bf(xs[c]);
        ph.u[c] = h;
        pl.u[c] = f2bf(xs[c] - bf2f(h));
    }
    ((uint2*)hi)[off4 + i] = ph.v;
    ((uint2*)lo)[off4 + i] = pl.v;
}

// ---------------------------------------------------------------------------
// MFMA GEMM: C[m,n] = sum_k Xbf[m,k] * W[n,k] + bias; X single bf16, W hi/lo
// (2 MFMAs per tile-pair). mat 0 -> Q hi/lo, 1 -> K hi/lo, 2 -> V f32.
// ---------------------------------------------------------------------------
#define BM 128
#define BN 128
#define BK 32

__global__ __launch_bounds__(256)
void gemm_split(const ushort_t* __restrict__ A,
                const ushort_t* __restrict__ Bhi, const ushort_t* __restrict__ Blo,
                const float* __restrict__ bq, const float* __restrict__ bk,
                const float* __restrict__ bv,
                ushort_t* __restrict__ qhi, ushort_t* __restrict__ qlo,
                ushort_t* __restrict__ khi, ushort_t* __restrict__ klo,
                float* __restrict__ outv)
{
    __shared__ ushort_t Ah[BM*BK], Bh[BN*BK], Bl[BN*BK];  // 24 KB

    const int tid  = threadIdx.x;
    const int lane = tid & 63, wave = tid >> 6;
    const int m0 = blockIdx.y * BM, n0 = blockIdx.x * BN;
    const int wm = (wave >> 1) * 64, wn = (wave & 1) * 64;

    f32x4 acc[4][4];
    #pragma unroll
    for (int i=0;i<4;i++)
        #pragma unroll
        for (int j=0;j<4;j++) acc[i][j] = (f32x4){0.f,0.f,0.f,0.f};

    const int r0 = tid >> 2, c0 = (tid & 3) * 8;
    const size_t ga0 = (size_t)(m0 + r0)      * D_ + c0;
    const size_t ga1 = (size_t)(m0 + 64 + r0) * D_ + c0;
    const size_t gb0 = (size_t)(n0 + r0)      * D_ + c0;
    const size_t gb1 = (size_t)(n0 + 64 + r0) * D_ + c0;
    const int l0 = wave * 512;
    const int l1 = 2048 + wave * 512;

    const int fr = lane & 15, kc = (lane >> 4) * 8;

    for (int k0 = 0; k0 < D_; k0 += BK) {
        cp16(A   + ga0 + k0, Ah + l0);
        cp16(A   + ga1 + k0, Ah + l1);
        cp16(Bhi + gb0 + k0, Bh + l0);
        cp16(Bhi + gb1 + k0, Bh + l1);
        cp16(Blo + gb0 + k0, Bl + l0);
        cp16(Blo + gb1 + k0, Bl + l1);
        __syncthreads();

        bf16x8 fa[4], fbh[4], fbl[4];
        #pragma unroll
        for (int i = 0; i < 4; i++){
            fa[i]  = *(const bf16x8*)&Ah[(wm + i*16 + fr)*BK + kc];
            fbh[i] = *(const bf16x8*)&Bh[(wn + i*16 + fr)*BK + kc];
            fbl[i] = *(const bf16x8*)&Bl[(wn + i*16 + fr)*BK + kc];
        }
        #pragma unroll
        for (int i = 0; i < 4; i++)
            #pragma unroll
            for (int j = 0; j < 4; j++){
                acc[i][j] = __builtin_amdgcn_mfma_f32_16x16x32_bf16(fa[i], fbh[j], acc[i][j], 0,0,0);
                acc[i][j] = __builtin_amdgcn_mfma_f32_16x16x32_bf16(fa[i], fbl[j], acc[i][j], 0,0,0);
            }
        __syncthreads();
    }

    const int mat = n0 / D_;   // block-uniform
    const float* bias = (mat==0) ? bq : (mat==1) ? bk : bv;
    const int col = lane & 15, rbase = (lane >> 4) * 4;
    #pragma unroll
    for (int j = 0; j < 4; j++){
        int nn = n0 + wn + j*16 + col - mat*D_;
        int h = nn >> 6, d = nn & 63;
        float bsv = bias[nn];
        #pragma unroll
        for (int i = 0; i < 4; i++){
            #pragma unroll
            for (int r = 0; r < 4; r++){
                int m = m0 + wm + i*16 + rbase + r;
                int bb = m >> 9, s = m & 511;
                size_t idx = (((size_t)bb*H_ + h)*S_ + s)*DH_ + d;
                float val = acc[i][j][r] + bsv;
                if (mat == 2) outv[idx] = val;
                else {
                    ushort_t hv = f2bf(val);
                    ushort_t lv = f2bf(val - bf2f(hv));
                    if (mat == 0){ qhi[idx] = hv; qlo[idx] = lv; }
                    else         { khi[idx] = hv; klo[idx] = lv; }
                }
            }
        }
    }
}

// ---------------------------------------------------------------------------
// MFMA sparsemax attention, quad-owns-row layout (DS-pipe minimized).
// Block = (head, 16 q-rows), 256 threads. Phase 1: wave w computes scores
// for 16 rows x keys [128w,128w+128) -> LDS sc[row][ownerLane][36].
// Phase 2: quad q of wave w owns row w*4+q entirely (32 keys/lane over 16
// lanes). All reductions are 4-step intra-quad butterflies (4 rows per
// shfl instruction). PV: quad-sliced ballot walk, float4 V loads (4 quads
// = 4 V rows per instruction). One barrier total.
// ---------------------------------------------------------------------------
__global__ __launch_bounds__(256)
void attn_mfma(const ushort_t* __restrict__ Qhi, const ushort_t* __restrict__ Qlo,
               const ushort_t* __restrict__ Khi, const ushort_t* __restrict__ Klo,
               const float* __restrict__ V, const float* __restrict__ mask,
               float* __restrict__ out)
{
    __shared__ float sc[16*16*36];   // 36 KB: [row][owner][36]

    const int lane = threadIdx.x & 63;
    const int wave = threadIdx.x >> 6;         // 0..3
    const int fr = lane & 15, quad = lane >> 4;
    const int bh = blockIdx.x >> 5;            // same-head blocks adjacent
    const int q0 = (blockIdx.x & 31) * 16;
    const int b = bh / H_, h = bh % H_;
    const size_t hb = (size_t)bh * S_ * DH_;
    const int kw0 = wave * 128;                // phase-1 key range

    // ---- Phase 1: QK^T scores (Q hi/lo x K hi/lo, 6 MFMAs per tile) -------
    bf16x8 qh[2], ql[2];
    {
        const ushort_t* qp  = Qhi + hb + (size_t)(q0 + fr)*DH_ + quad*8;
        const ushort_t* qp2 = Qlo + hb + (size_t)(q0 + fr)*DH_ + quad*8;
        qh[0] = *(const bf16x8*)qp;   qh[1] = *(const bf16x8*)(qp + 32);
        ql[0] = *(const bf16x8*)qp2;  ql[1] = *(const bf16x8*)(qp2 + 32);
    }

    f32x4 acc[8];
    #pragma unroll
    for (int j=0;j<8;j++) acc[j] = (f32x4){0.f,0.f,0.f,0.f};

    #pragma unroll
    for (int j=0;j<8;j++){
        const ushort_t* kp  = Khi + hb + (size_t)(kw0 + j*16 + fr)*DH_ + quad*8;
        const ushort_t* kp2 = Klo + hb + (size_t)(kw0 + j*16 + fr)*DH_ + quad*8;
        bf16x8 kh0 = *(const bf16x8*)kp;
        bf16x8 kh1 = *(const bf16x8*)(kp + 32);
        bf16x8 kl0 = *(const bf16x8*)kp2;
        bf16x8 kl1 = *(const bf16x8*)(kp2 + 32);
        acc[j] = __builtin_amdgcn_mfma_f32_16x16x32_bf16(qh[0], kh0, acc[j], 0,0,0);
        acc[j] = __builtin_amdgcn_mfma_f32_16x16x32_bf16(qh[1], kh1, acc[j], 0,0,0);
        acc[j] = __builtin_amdgcn_mfma_f32_16x16x32_bf16(ql[0], kh0, acc[j], 0,0,0);
        acc[j] = __builtin_amdgcn_mfma_f32_16x16x32_bf16(ql[1], kh1, acc[j], 0,0,0);
        acc[j] = __builtin_amdgcn_mfma_f32_16x16x32_bf16(qh[0], kl0, acc[j], 0,0,0);
        acc[j] = __builtin_amdgcn_mfma_f32_16x16x32_bf16(qh[1], kl1, acc[j], 0,0,0);
    }

    // scale + mask, scatter to owner layout: key k -> slot k>>5, pos k&31
    const float* mrow = mask + b * S_;
    #pragma unroll
    for (int j=0;j<8;j++){
        int k = kw0 + j*16 + fr;
        float mv = mrow[k];
        int base = (k >> 5)*36 + (k & 31);
        #pragma unroll
        for (int r=0;r<4;r++){
            int row = quad*4 + r;
            sc[row*576 + base] = acc[j][r]*0.125f + mv;
        }
    }
    __syncthreads();

    // ---- Phase 2: quad q of wave w owns row w*4+q; lane fr holds keys
    //      [fr*32, fr*32+32) of that row.
    const int row = wave*4 + quad;
    float z[32];
    {
        const float* zp = &sc[row*576 + fr*36];
        #pragma unroll
        for (int jj=0;jj<8;jj++){
            float4 t = *(const float4*)(zp + jj*4);
            z[jj*4+0]=t.x; z[jj*4+1]=t.y; z[jj*4+2]=t.z; z[jj*4+3]=t.w;
        }
    }

    // row max: 31 VALU + 4-step intra-quad butterfly (handles 4 rows at once)
    float tau;
    {
        float mm = z[0];
        #pragma unroll
        for (int i=1;i<32;i++) mm = fmaxf(mm, z[i]);
        #pragma unroll
        for (int off=1; off<16; off<<=1) mm = fmaxf(mm, __shfl_xor(mm, off, 64));
        tau = mm - 1.0f;
    }

    // Michelot fixed-point: 2 values x 4 butterfly steps = 8 DS ops/iter
    for (int it=0; it<16; it++){
        float ss = 0.f, kk = 0.f;
        #pragma unroll
        for (int i=0;i<32;i++){
            float zz = z[i];
            if (zz > tau){ ss += zz; kk += 1.f; }
        }
        #pragma unroll
        for (int off=1; off<16; off<<=1){
            ss += __shfl_xor(ss, off, 64);
            kk += __shfl_xor(kk, off, 64);
        }
        float tn = (ss - 1.0f) / kk;
        bool changed = (tn != tau);
        tau = tn;
        if (!__any(changed)) break;
    }

    // PV: per-quad ballot walk; key = 32*srcLane + i; 4 quads load 4 V rows
    // per instruction (each quad: 16 lanes x float4 = 256B coalesced).
    float4 ctx = make_float4(0.f, 0.f, 0.f, 0.f);
    const float* vb = V + hb;
    #pragma unroll
    for (int i=0;i<32;i++){
        float p = z[i] - tau;
        unsigned long long bal = __ballot(p > 0.f);
        unsigned mk = (unsigned)((bal >> (quad*16)) & 0xFFFFull);
        while (mk){
            int s = __ffs(mk) - 1;
            mk &= mk - 1;
            float pv = __shfl(p, quad*16 + s, 64);
            const float4 vv = *(const float4*)(vb + (size_t)(s*32 + i)*DH_ + fr*4);
            ctx.x += pv * vv.x;
            ctx.y += pv * vv.y;
            ctx.z += pv * vv.z;
            ctx.w += pv * vv.w;
        }
    }

    *(float4*)(out + (size_t)(b*S_ + q0 + row)*D_ + h*DH_ + fr*4) = ctx;
}

// ---------------------------------------------------------------------------
extern "C" void kernel_launch(void* const* d_in, const int* in_sizes, int n_in,
                              void* d_out, int out_size, void* d_ws, size_t ws_size,
                              hipStream_t stream) {
    const float* hs   = (const float*)d_in[0];
    const float* mask = (const float*)d_in[1];
    const float* Wq   = (const float*)d_in[2];
    const float* bq   = (const float*)d_in[3];
    const float* Wk   = (const float*)d_in[4];
    const float* bk   = (const float*)d_in[5];
    const float* Wv   = (const float*)d_in[6];
    const float* bv   = (const float*)d_in[7];
    float* out = (float*)d_out;

    const size_t per = (size_t)BH_ * S_ * DH_;   // 6291456
    char* w = (char*)d_ws;
    float*    vb  = (float*)w;    w += per*4;
    ushort_t* qhi = (ushort_t*)w; w += per*2;
    ushort_t* qlo = (ushort_t*)w; w += per*2;
    ushort_t* khi = (ushort_t*)w; w += per*2;
    ushort_t* klo = (ushort_t*)w; w += per*2;
    ushort_t* Xbf = (ushort_t*)w; w += per*2;
    ushort_t* Whi = (ushort_t*)w; w += (size_t)NTOT*D_*2;
    ushort_t* Wlo = (ushort_t*)w;

    convert_x<<<(int)(per/4/256), 256, 0, stream>>>(hs, Xbf, (int)(per/4));
    convert_w<<<dim3(D_*D_/4/256, 1, 3), 256, 0, stream>>>(Wq, Wk, Wv, Whi, Wlo);

    dim3 ggrid(NTOT/BN, MTOT/BM);   // (18, 64)
    gemm_split<<<ggrid, 256, 0, stream>>>(Xbf, Whi, Wlo, bq, bk, bv,
                                          qhi, qlo, khi, klo, vb);

    attn_mfma<<<BH_*32, 256, 0, stream>>>(qhi, qlo, khi, klo, vb, mask, out);
}